// Round 6
// baseline (84.307 us; speedup 1.0000x reference)
//
#include <hip/hip_runtime.h>
#include <hip/hip_bf16.h>

typedef __attribute__((ext_vector_type(8))) short short8_t;
typedef __attribute__((ext_vector_type(4))) float f32x4;

#define BATCH 16
#define CIN   512
#define COUT  512
#define TT    4096
#define BK    64
#define NKT   (CIN / BK)   // 8 K-steps

// pack 2 f32 -> u32 of 2 bf16 (RNE)
__device__ __forceinline__ uint pk2(float a, float b) {
    ushort lo = __builtin_bit_cast(ushort, __float2bfloat16(a));
    ushort hi = __builtin_bit_cast(ushort, __float2bfloat16(b));
    return (uint)lo | ((uint)hi << 16);
}

// Raw barrier: LDS writes visible, but VMEM loads may stay in flight across it
// (unlike __syncthreads, which the compiler guards with vmcnt(0)).
__device__ __forceinline__ void barrier_seq() {
    asm volatile("s_waitcnt lgkmcnt(0)" ::: "memory");
    __builtin_amdgcn_sched_barrier(0);
    __builtin_amdgcn_s_barrier();
    __builtin_amdgcn_sched_barrier(0);
}

// ---------------------------------------------------------------------------
// Pre-pass: W (fp32 [512][512]) -> bf16 fragment order (unchanged from R5):
//   Wb[bm][ksg][g][r][8k], bm=m>>4, r=m&15, ksg=k>>5, g=(k>>3)&3
// ---------------------------------------------------------------------------
extern "C" __global__ __launch_bounds__(256)
void wconv(const float* __restrict__ W, ushort* __restrict__ Wb)
{
    const int i  = blockIdx.x * 256 + threadIdx.x;   // [0, 65536)
    const int m  = i >> 7;
    const int k0 = (i & 127) * 4;
    const float4 v = *(const float4*)(W + (size_t)m * CIN + k0);
    const int bm = m >> 4, r = m & 15;
    const int ksg = k0 >> 5, g = (k0 >> 3) & 3, k7 = k0 & 7;
    uint2 q;
    q.x = pk2(v.x, v.y);
    q.y = pk2(v.z, v.w);
    *(uint2*)&Wb[(size_t)bm * 8192 + ksg * 512 + g * 128 + r * 8 + k7] = q;
}

// ---------------------------------------------------------------------------
// Main GEMM: tile 128m x 64n, BK=64 (8 steps), 4 waves (wave 32m x 64n).
// A: fragment-direct global loads (Wb, L2-hot). B: 2-deep reg staging ->
// bf16 LDS double buffer. Raw s_barrier (no vmcnt drain) + sched_barrier
// fences pin: B(t+2) issued at step t, consumed (cvt+write) at step t+1.
// LDS: LB[buf][p][n'][8k] ushort, p=k>>3, n' = n ^ (p&1): write and read are
// both exactly 8 lanes per bank-group -> conflict-free.
// ---------------------------------------------------------------------------
template<bool WSB>
__global__ __launch_bounds__(256)
void conv2x1_gemm(const float* __restrict__ pre, const float* __restrict__ W,
                  const ushort* __restrict__ Wb,
                  const float* __restrict__ bias, float* __restrict__ out)
{
    __shared__ alignas(16) ushort LB[2][8 * 64 * 8];   // 2 x 8 KiB

    const int tid  = threadIdx.x;
    const int lane = tid & 63;
    const int wm   = tid >> 6;          // wave = m-strip [0,4)
    const int g    = lane >> 4;
    const int l15  = lane & 15;

    // XCD-chunked bijective swizzle (4096 = 8*512); ids id..id+3 share a
    // B-panel (same bb, ti) on one XCD's L2.
    const int id   = ((blockIdx.x & 7) << 9) | (blockIdx.x >> 3);
    const int mblk = id & 3;
    const int ti   = (id >> 2) & 63;
    const int bb   = id >> 8;

    const int m0 = mblk << 7;   // [0,512) step 128
    const int t0 = ti << 6;     // [0,4096) step 64

    const float* preB   = pre + (size_t)bb * ((size_t)CIN * TT);
    const int    bmBase = (m0 >> 4) + wm * 2;

    // B staging: thread covers 8k x 2t. p = k-octet plane, t = 2*b_tq.
    const int b_p  = tid >> 5;          // [0,8)
    const int b_tq = tid & 31;          // [0,32)

    float2   brA[8], brB[8];   // raw f32, 2-deep
    short8_t af[2][2];         // A fragments [ks][mi], current step

    f32x4 acc[2][4];
#pragma unroll
    for (int i = 0; i < 2; ++i)
#pragma unroll
        for (int j = 0; j < 4; ++j) acc[i][j] = (f32x4)0.0f;

#define LOAD_A(KT) do { \
    if constexpr (WSB) { \
        _Pragma("unroll") \
        for (int ks = 0; ks < 2; ++ks) \
            _Pragma("unroll") \
            for (int mi = 0; mi < 2; ++mi) \
                af[ks][mi] = *(const short8_t*)(Wb + (size_t)(bmBase + mi) * 8192 \
                                                + ((KT)*2 + ks) * 512 + g * 128 + l15 * 8); \
    } else { \
        _Pragma("unroll") \
        for (int ks = 0; ks < 2; ++ks) \
            _Pragma("unroll") \
            for (int mi = 0; mi < 2; ++mi) { \
                const float* ab = W + (size_t)(m0 + wm*32 + mi*16 + l15) * CIN \
                                  + (KT)*BK + ks*32 + g*8; \
                const float4 u0 = *(const float4*)ab; \
                const float4 u1 = *(const float4*)(ab + 4); \
                uint4 qq; \
                qq.x = pk2(u0.x, u0.y); qq.y = pk2(u0.z, u0.w); \
                qq.z = pk2(u1.x, u1.y); qq.w = pk2(u1.z, u1.w); \
                af[ks][mi] = __builtin_bit_cast(short8_t, qq); \
            } \
    } } while (0)

#define LOAD_B(KT, BR) do { \
    _Pragma("unroll") \
    for (int j = 0; j < 8; ++j) \
        BR[j] = *(const float2*)(preB + (size_t)((KT)*BK + b_p*8 + j) * TT + t0 + 2*b_tq); \
    } while (0)

#define CVT_WRITE(BUF, BR) do { \
    _Pragma("unroll") \
    for (int tt = 0; tt < 2; ++tt) { \
        uint4 q; \
        q.x = pk2(((const float*)&BR[0])[tt], ((const float*)&BR[1])[tt]); \
        q.y = pk2(((const float*)&BR[2])[tt], ((const float*)&BR[3])[tt]); \
        q.z = pk2(((const float*)&BR[4])[tt], ((const float*)&BR[5])[tt]); \
        q.w = pk2(((const float*)&BR[6])[tt], ((const float*)&BR[7])[tt]); \
        const int n  = 2*b_tq + tt; \
        const int np = n ^ (b_p & 1); \
        *(uint4*)&LB[BUF][b_p * 512 + np * 8] = q; \
    } } while (0)

#define COMPUTE(BUF) do { \
    _Pragma("unroll") \
    for (int ks = 0; ks < 2; ++ks) { \
        short8_t bf[4]; \
        _Pragma("unroll") \
        for (int ni = 0; ni < 4; ++ni) { \
            const int n  = ni*16 + l15; \
            const int p  = ks*4 + g; \
            const int np = n ^ (p & 1); \
            bf[ni] = *(const short8_t*)&LB[BUF][p * 512 + np * 8]; \
        } \
        _Pragma("unroll") \
        for (int mi = 0; mi < 2; ++mi) \
            _Pragma("unroll") \
            for (int ni = 0; ni < 4; ++ni) \
                acc[mi][ni] = __builtin_amdgcn_mfma_f32_16x16x32_bf16(af[ks][mi], bf[ni], acc[mi][ni], 0, 0, 0); \
    } } while (0)

    // -------- prologue --------
    LOAD_A(0);              // oldest in vmcnt FIFO
    LOAD_B(0, brA);
    LOAD_B(1, brB);
    CVT_WRITE(0, brA);      // waits A(0)+B(0); B(1) stays in flight
    barrier_seq();

    // -------- main loop: B(kt+2) issued at step kt, written at step kt+1 --------
#pragma unroll
    for (int kt = 0; kt < NKT; ++kt) {
        if ((kt & 1) == 0) { if (kt + 2 < NKT) LOAD_B(kt + 2, brA); }
        else               { if (kt + 2 < NKT) LOAD_B(kt + 2, brB); }
        __builtin_amdgcn_sched_barrier(0);
        if ((kt & 1) == 0) COMPUTE(0); else COMPUTE(1);
        if (kt + 1 < NKT) LOAD_A(kt + 1);
        __builtin_amdgcn_sched_barrier(0);
        if (kt + 1 < NKT) {
            if ((kt & 1) == 0) CVT_WRITE(1, brB);   // B(kt+1), issued a full step ago
            else               CVT_WRITE(0, brA);
            barrier_seq();
        }
    }

    // -------- epilogue: out = 2*(acc + bias) --------
    const int orow = m0 + wm*32 + g*4;     // + mi*16 + r
    float bv[2][4];
#pragma unroll
    for (int mi = 0; mi < 2; ++mi)
#pragma unroll
        for (int r = 0; r < 4; ++r)
            bv[mi][r] = bias[orow + mi*16 + r];

    float* outB = out + (size_t)bb * ((size_t)COUT * TT);
#pragma unroll
    for (int mi = 0; mi < 2; ++mi) {
#pragma unroll
        for (int ni = 0; ni < 4; ++ni) {
            const int t = t0 + ni*16 + l15;
#pragma unroll
            for (int r = 0; r < 4; ++r) {
                const int o = orow + mi*16 + r;
                outB[(size_t)o * TT + t] = 2.0f * (acc[mi][ni][r] + bv[mi][r]);
            }
        }
    }
}

extern "C" void kernel_launch(void* const* d_in, const int* in_sizes, int n_in,
                              void* d_out, int out_size, void* d_ws, size_t ws_size,
                              hipStream_t stream)
{
    const float* pre  = (const float*)d_in[0];   // [16, 512, 4096] fp32
    const float* Wp   = (const float*)d_in[1];   // [512, 512] fp32
    const float* bias = (const float*)d_in[2];   // [512] fp32
    float* out = (float*)d_out;                  // [16, 512, 4096] fp32

    const bool usews = (ws_size >= (size_t)(COUT * CIN * sizeof(ushort)));  // 512 KiB

    if (usews) {
        ushort* Wb = (ushort*)d_ws;
        hipLaunchKernelGGL(wconv, dim3(256), dim3(256), 0, stream, Wp, Wb);
        hipLaunchKernelGGL((conv2x1_gemm<true>), dim3(BATCH * 4 * 64), dim3(256), 0, stream,
                           pre, Wp, Wb, bias, out);
    } else {
        hipLaunchKernelGGL((conv2x1_gemm<false>), dim3(BATCH * 4 * 64), dim3(256), 0, stream,
                           pre, Wp, (const ushort*)nullptr, bias, out);
    }
}